// Round 9
// baseline (285.087 us; speedup 1.0000x reference)
//
#include <hip/hip_runtime.h>
#include <hip/hip_bf16.h>

typedef unsigned short ushort_t;
typedef unsigned int u32;
typedef unsigned long long u64;
typedef _Float16 f16;
typedef __attribute__((ext_vector_type(8))) _Float16 v8h;
typedef __attribute__((ext_vector_type(4))) float v4f;

#define M_TOK 16384        // 8 * 2048 tokens
#define DDIM 512
#define NCODES 8192
#define NTILE 32           // NCODES / 256
#define BKT 32             // K per tile
#define NT 16              // 512 / BKT

// workspace layout (bytes)
#define OFF_AH   0u            // 16 MB  f16(x)
#define OFF_BH   16777216u     //  8 MB  f16(cb)
#define OFF_PART 25165824u     //  4 MB  u64 per (token, ntile)
#define OFF_C2   33554432u     // 32 KB
#define OFF_ACC  33587200u     //  4 B

__global__ void zero_kernel(float* __restrict__ acc) {
    if (threadIdx.x == 0 && blockIdx.x == 0) *acc = 0.f;
}

// ---------------- cb: fp32 -> f16 + c2 in one pass (1 row per wave) -------
__global__ void split_cb_c2_kernel(const float* __restrict__ cb, ushort_t* __restrict__ Bh,
                                   float* __restrict__ c2) {
    int row  = blockIdx.x * 4 + (threadIdx.x >> 6);
    int l    = threadIdx.x & 63;
    const float* p = cb + (size_t)row * DDIM + l * 8;
    float4 a = *(const float4*)p;
    float4 b = *(const float4*)(p + 4);
    float v[8] = {a.x, a.y, a.z, a.w, b.x, b.y, b.z, b.w};
    union { ushort_t u[8]; uint4 q; } H;
    float s = 0.f;
    #pragma unroll
    for (int j = 0; j < 8; ++j) {
        f16 h = (f16)v[j];
        __builtin_memcpy(&H.u[j], &h, 2);
        s += v[j] * v[j];
    }
    *(uint4*)(Bh + (size_t)row * DDIM + l * 8) = H.q;
    #pragma unroll
    for (int off = 32; off; off >>= 1) s += __shfl_down(s, off);
    if (l == 0) c2[row] = s;
}

// ---------------- x: fp32 -> f16, 8 elems/thread ----------------
__global__ void split_hi_kernel(const float* __restrict__ src, ushort_t* __restrict__ hi, int n8) {
    int i = blockIdx.x * blockDim.x + threadIdx.x;
    if (i >= n8) return;
    const float4* s4 = (const float4*)src + (size_t)i * 2;
    float4 a = s4[0], b = s4[1];
    float v[8] = {a.x, a.y, a.z, a.w, b.x, b.y, b.z, b.w};
    union { ushort_t u[8]; uint4 q; } H;
    #pragma unroll
    for (int j = 0; j < 8; ++j) {
        f16 h = (f16)v[j];
        __builtin_memcpy(&H.u[j], &h, 2);
    }
    *(uint4*)(hi + (size_t)i * 8) = H.q;
}

// ---- MFMA f16 GEMM: 256x256 tile, 8 waves (2Mx4N, 128x64/wave), BK=32, ----
// ---- triple-buffered LDS, no-drain counted vmcnt, 2-phase/tile, top-1 -----
__launch_bounds__(512, 2)
__global__ void gemm_top1_kernel(const ushort_t* __restrict__ Ah, const ushort_t* __restrict__ Bh,
                                 const float* __restrict__ c2, u64* __restrict__ part) {
    __shared__ __align__(16) ushort_t Asb[3][256 * BKT];   // 3 x 16 KB
    __shared__ __align__(16) ushort_t Bsb[3][256 * BKT];   // 3 x 16 KB
    __shared__ u64 mergebuf[256][4];                       // 8 KB

    const int tid = threadIdx.x;
    const int wid = tid >> 6;
    const int l   = tid & 63;
    const int wr  = wid >> 2;               // 0..1 (M)
    const int wn  = wid & 3;                // 0..3 (N)
    const int mtile = blockIdx.x >> 5;      // 0..63
    const int ntile = blockIdx.x & 31;      // 0..31
    const int row0 = mtile * 256;
    const int col0 = ntile * 256;

    const int lg = l >> 4;                  // lane group 0..3
    const int lc = l & 15;

    // staging: per gld round, 128 rows x 64B; lane -> row (tid>>2), slot (l&3).
    // LDS[row][s] holds global k-slot s ^ ((row>>1)&3)  (verified r8 formulas).
    const int sslot = (l & 3) ^ ((l >> 3) & 3);     // pre-swizzled source slot

    // 4 global_load_lds per thread per STAGE (2 A + 2 B), tile kt -> buf kt%3
    auto STAGE = [&](int buf, int kt) {
        const int k0 = kt * BKT;
        #pragma unroll
        for (int i = 0; i < 2; ++i) {
            int rbase = i * 128 + wid * 16;
            int row = rbase + (l >> 2);
            const ushort_t* ga = Ah + (size_t)(row0 + row) * DDIM + k0 + sslot * 8;
            __builtin_amdgcn_global_load_lds(
                (const __attribute__((address_space(1))) void*)ga,
                (__attribute__((address_space(3))) void*)&Asb[buf][rbase * BKT], 16, 0, 0);
            const ushort_t* gb = Bh + (size_t)(col0 + row) * DDIM + k0 + sslot * 8;
            __builtin_amdgcn_global_load_lds(
                (const __attribute__((address_space(1))) void*)gb,
                (__attribute__((address_space(3))) void*)&Bsb[buf][rbase * BKT], 16, 0, 0);
        }
    };

    v4f acc[8][4];
    #pragma unroll
    for (int m = 0; m < 8; ++m)
        #pragma unroll
        for (int n = 0; n < 4; ++n) acc[m][n] = (v4f){0.f, 0.f, 0.f, 0.f};

    // prologue: stage tiles 0 and 1 (8 glds in flight)
    STAGE(0, 0);
    STAGE(1, 1);

    const int slotbyte = (lg ^ ((lc >> 1) & 3)) * 16;   // read swizzle (r8-verified)

    for (int t = 0; t < NT; ++t) {
        const int buf = t % 3;
        // tile top: wait own tile-t stages (4 newest = tile t+1's stay in flight),
        // then barrier -> ALL waves' tile-t data visible. Never drains mid-loop.
        if (t < NT - 1) {
            asm volatile("s_waitcnt vmcnt(4)" ::: "memory");
        } else {
            asm volatile("s_waitcnt vmcnt(0)" ::: "memory");
        }
        asm volatile("s_barrier" ::: "memory");

        v8h bf[4];
        // ---- phase 0: read bf (all) + af[0..3]; stage A-rounds of t+2 ----
        {
            v8h af[4];
            #pragma unroll
            for (int n = 0; n < 4; ++n) {
                int row = wn * 64 + n * 16 + lc;
                bf[n] = *(const v8h*)((const char*)&Bsb[buf][0] + row * 64 + slotbyte);
            }
            #pragma unroll
            for (int mm = 0; mm < 4; ++mm) {
                int row = wr * 128 + mm * 16 + lc;
                af[mm] = *(const v8h*)((const char*)&Asb[buf][0] + row * 64 + slotbyte);
            }
            if (t + 2 < NT) STAGE((t + 2) % 3, t + 2);
            asm volatile("s_barrier" ::: "memory");            // phase barrier
            asm volatile("s_waitcnt lgkmcnt(0)" ::: "memory"); // my reads done
            __builtin_amdgcn_sched_barrier(0);
            __builtin_amdgcn_s_setprio(1);
            #pragma unroll
            for (int mm = 0; mm < 4; ++mm)
                #pragma unroll
                for (int n = 0; n < 4; ++n)
                    acc[mm][n] = __builtin_amdgcn_mfma_f32_16x16x32_f16(af[mm], bf[n], acc[mm][n], 0, 0, 0);
            __builtin_amdgcn_s_setprio(0);
        }
        // ---- phase 1: read af[4..7] ----
        {
            v8h af[4];
            #pragma unroll
            for (int mm = 0; mm < 4; ++mm) {
                int row = wr * 128 + (4 + mm) * 16 + lc;
                af[mm] = *(const v8h*)((const char*)&Asb[buf][0] + row * 64 + slotbyte);
            }
            asm volatile("s_barrier" ::: "memory");            // phase barrier
            asm volatile("s_waitcnt lgkmcnt(0)" ::: "memory");
            __builtin_amdgcn_sched_barrier(0);
            __builtin_amdgcn_s_setprio(1);
            #pragma unroll
            for (int mm = 0; mm < 4; ++mm)
                #pragma unroll
                for (int n = 0; n < 4; ++n)
                    acc[4 + mm][n] = __builtin_amdgcn_mfma_f32_16x16x32_f16(af[mm], bf[n], acc[4 + mm][n], 0, 0, 0);
            __builtin_amdgcn_s_setprio(0);
        }
    }

    // ---- epilogue: per-row min over this wave's 64 cols, packed u64 ----
    // D layout: col = lc, row = lg*4 + j (verified rounds 3/4/6/8)
    float c2v[4];
    #pragma unroll
    for (int n = 0; n < 4; ++n) c2v[n] = c2[col0 + wn * 64 + n * 16 + lc];

    #pragma unroll
    for (int m = 0; m < 8; ++m) {
        #pragma unroll
        for (int j = 0; j < 4; ++j) {
            int rloc = wr * 128 + m * 16 + lg * 4 + j;
            u64 best = ~0ull;
            #pragma unroll
            for (int n = 0; n < 4; ++n) {
                float s = c2v[n] - 2.0f * acc[m][n][j];
                u32 b = __float_as_uint(s);
                b = (b & 0x80000000u) ? ~b : (b | 0x80000000u);   // monotone float->u32
                int col = col0 + wn * 64 + n * 16 + lc;
                u64 key = ((u64)b << 32) | (u32)col;              // low bits: index tie-break
                best = key < best ? key : best;
            }
            #pragma unroll
            for (int off = 1; off < 16; off <<= 1) {
                u64 o = __shfl_xor(best, off);
                best = o < best ? o : best;
            }
            if (lc == 0) mergebuf[rloc][wn] = best;
        }
    }
    __syncthreads();   // full drain before cross-wave merge read
    if (tid < 256) {
        u64 a = mergebuf[tid][0], b = mergebuf[tid][1];
        u64 c = mergebuf[tid][2], d = mergebuf[tid][3];
        u64 ab = a < b ? a : b;
        u64 cd = c < d ? c : d;
        part[(size_t)(row0 + tid) * NTILE + ntile] = ab < cd ? ab : cd;
    }
}

// ---- merge 32 winners -> top-4, fp64 recheck, quantize + idx + loss ------
__global__ void reduce_quant_kernel(const u64* __restrict__ part,
                                    const float* __restrict__ x, const float* __restrict__ cb,
                                    float* __restrict__ out, float* __restrict__ acc) {
    __shared__ float red[4];
    int t = blockIdx.x * 4 + (threadIdx.x >> 6);
    int l = threadIdx.x & 63;
    u64 k = (l < NTILE) ? part[(size_t)t * NTILE + l] : ~0ull;

    int cand[4];
    #pragma unroll
    for (int c = 0; c < 4; ++c) {
        u64 m = k;
        #pragma unroll
        for (int off = 1; off < 64; off <<= 1) {
            u64 o = __shfl_xor(m, off);
            m = o < m ? o : m;
        }
        cand[c] = (int)(u32)(m & 0xffffffffull);
        if (k == m) k = ~0ull;        // real keys unique (distinct cols) -> removes one lane
    }

    const float* xp = x + (size_t)t * DDIM + l * 8;
    float xv[8];
    #pragma unroll
    for (int j = 0; j < 8; ++j) xv[j] = xp[j];

    float cp[4][8];
    double d[4];
    #pragma unroll
    for (int c = 0; c < 4; ++c) {
        const float* cpp = cb + (size_t)cand[c] * DDIM + l * 8;
        double s = 0.0;
        #pragma unroll
        for (int j = 0; j < 8; ++j) {
            cp[c][j] = cpp[j];
            double a = (double)cp[c][j] - (double)xv[j];
            s += a * a;
        }
        d[c] = s;
    }
    #pragma unroll
    for (int c = 0; c < 4; ++c) {
        #pragma unroll
        for (int off = 1; off < 64; off <<= 1) d[c] += __shfl_xor(d[c], off);
    }

    double bd = d[0]; int bi = cand[0]; int bc = 0;
    #pragma unroll
    for (int c = 1; c < 4; ++c)
        if (d[c] < bd || (d[c] == bd && cand[c] < bi)) { bd = d[c]; bi = cand[c]; bc = c; }

    // winning code row (compile-time-indexed select, rule #20)
    float cw[8];
    #pragma unroll
    for (int j = 0; j < 8; ++j) {
        float v = cp[0][j];
        #pragma unroll
        for (int c = 1; c < 4; ++c) v = (bc == c) ? cp[c][j] : v;
        cw[j] = v;
    }

    // quantized out = x + (codes - x); loss partial = sum diff^2
    float ls = 0.f;
    float4 o0, o1;
    float dj[8];
    #pragma unroll
    for (int j = 0; j < 8; ++j) { dj[j] = cw[j] - xv[j]; ls += dj[j] * dj[j]; }
    o0.x = xv[0] + dj[0]; o0.y = xv[1] + dj[1]; o0.z = xv[2] + dj[2]; o0.w = xv[3] + dj[3];
    o1.x = xv[4] + dj[4]; o1.y = xv[5] + dj[5]; o1.z = xv[6] + dj[6]; o1.w = xv[7] + dj[7];
    float* op = out + (size_t)t * DDIM + l * 8;
    *(float4*)op = o0;
    *(float4*)(op + 4) = o1;

    if (l == 0) out[(size_t)M_TOK * DDIM + t] = (float)bi;   // index as fp32

    #pragma unroll
    for (int off = 32; off; off >>= 1) ls += __shfl_down(ls, off);
    int wv = threadIdx.x >> 6;
    if (l == 0) red[wv] = ls;
    __syncthreads();
    if (threadIdx.x == 0) atomicAdd(acc, red[0] + red[1] + red[2] + red[3]);
}

__global__ void loss_final_kernel(const float* __restrict__ acc, float* __restrict__ out) {
    if (threadIdx.x == 0 && blockIdx.x == 0) {
        float mean = (*acc) / (float)((size_t)M_TOK * DDIM);
        out[(size_t)M_TOK * DDIM + M_TOK] = 2.0f * mean;
    }
}

extern "C" void kernel_launch(void* const* d_in, const int* in_sizes, int n_in,
                              void* d_out, int out_size, void* d_ws, size_t ws_size,
                              hipStream_t stream) {
    const float* x  = (const float*)d_in[0];
    const float* cb = (const float*)d_in[1];
    float* out = (float*)d_out;
    char* ws = (char*)d_ws;

    ushort_t* Ah   = (ushort_t*)(ws + OFF_AH);
    ushort_t* Bh   = (ushort_t*)(ws + OFF_BH);
    u64*      part = (u64*)(ws + OFF_PART);
    float*    c2   = (float*)(ws + OFF_C2);
    float*    acc  = (float*)(ws + OFF_ACC);

    zero_kernel<<<1, 64, 0, stream>>>(acc);
    split_cb_c2_kernel<<<NCODES / 4, 256, 0, stream>>>(cb, Bh, c2);
    split_hi_kernel<<<(M_TOK * DDIM / 8) / 256, 256, 0, stream>>>(x, Ah, M_TOK * DDIM / 8);
    gemm_top1_kernel<<<(M_TOK / 256) * NTILE, 512, 0, stream>>>(Ah, Bh, c2, part);
    reduce_quant_kernel<<<M_TOK / 4, 256, 0, stream>>>(part, x, cb, out, acc);
    loss_final_kernel<<<1, 64, 0, stream>>>(acc, out);
}

// Round 10
// 196.715 us; speedup vs baseline: 1.4492x; 1.4492x over previous
//
#include <hip/hip_runtime.h>
#include <hip/hip_bf16.h>

typedef signed char s8;
typedef unsigned int u32;
typedef unsigned long long u64;
typedef __attribute__((ext_vector_type(4))) int v4i;

#define M_TOK 16384        // 8 * 2048 tokens
#define DDIM 512
#define NCODES 8192
#define NTILE 64           // NCODES / 128
#define BKB 64             // K-bytes (= K elems) per tile at i8
#define KCH 8              // 512 / 64

#define QS   25.4f         // 127/5  (clip at 5 sigma)
#define QINV (1.0f / (QS * QS))

// workspace layout (bytes)
#define OFF_A8   0u            //  8 MB  i8(x)
#define OFF_B8   8388608u      //  4 MB  i8(cb)
#define OFF_PART 12582912u     //  8 MB  u64 per (token, ntile)
#define OFF_C2   20971520u     // 32 KB
#define OFF_ACC  21004288u     //  4 B

__global__ void zero_kernel(float* __restrict__ acc) {
    if (threadIdx.x == 0 && blockIdx.x == 0) *acc = 0.f;
}

// ---------------- cb: fp32 -> i8 + c2 in one pass (1 row per wave) --------
__global__ void quant_cb_c2_kernel(const float* __restrict__ cb, s8* __restrict__ B8,
                                   float* __restrict__ c2) {
    int row  = blockIdx.x * 4 + (threadIdx.x >> 6);
    int l    = threadIdx.x & 63;
    const float* p = cb + (size_t)row * DDIM + l * 8;
    float4 a = *(const float4*)p;
    float4 b = *(const float4*)(p + 4);
    float v[8] = {a.x, a.y, a.z, a.w, b.x, b.y, b.z, b.w};
    union { s8 c[8]; uint2 q; } H;
    float s = 0.f;
    #pragma unroll
    for (int j = 0; j < 8; ++j) {
        int q = (int)rintf(fminf(fmaxf(v[j] * QS, -127.f), 127.f));
        H.c[j] = (s8)q;
        s += v[j] * v[j];
    }
    *(uint2*)(B8 + (size_t)row * DDIM + l * 8) = H.q;
    #pragma unroll
    for (int off = 32; off; off >>= 1) s += __shfl_down(s, off);
    if (l == 0) c2[row] = s;
}

// ---------------- x: fp32 -> i8, 16 elems/thread ----------------
__global__ void quant_x_kernel(const float* __restrict__ src, s8* __restrict__ dst, int n16) {
    int i = blockIdx.x * blockDim.x + threadIdx.x;
    if (i >= n16) return;
    const float4* s4 = (const float4*)src + (size_t)i * 4;
    union { s8 c[16]; uint4 q; } H;
    #pragma unroll
    for (int k = 0; k < 4; ++k) {
        float4 a = s4[k];
        float v[4] = {a.x, a.y, a.z, a.w};
        #pragma unroll
        for (int j = 0; j < 4; ++j) {
            int q = (int)rintf(fminf(fmaxf(v[j] * QS, -127.f), 127.f));
            H.c[k * 4 + j] = (s8)q;
        }
    }
    *(uint4*)(dst + (size_t)i * 16) = H.q;
}

// ---------------- i8 MFMA GEMM, BK=64 dbuf + counted vmcnt, top-1 ---------
// S[m][n] = q(x[m]).q(c[n]) exact int32; score = c2[n] - 2 S/QS^2.
// Block: 128x128, 4 waves. LDS: 2 x (8KB A + 8KB B) + 2KB merge = 34 KB -> 4 blocks/CU.
// Geometry byte-identical to round-8 (64 B/row, 4x16B slots, same swizzles).
__launch_bounds__(256, 4)
__global__ void gemm_top1_kernel(const s8* __restrict__ A8, const s8* __restrict__ B8,
                                 const float* __restrict__ c2, u64* __restrict__ part) {
    __shared__ __align__(16) s8 Asb[2][128 * BKB];   // 2 x 8 KB
    __shared__ __align__(16) s8 Bsb[2][128 * BKB];   // 2 x 8 KB
    __shared__ u64 mergebuf[128][2];

    const int tid = threadIdx.x;
    const int wid = tid >> 6;
    const int l   = tid & 63;
    const int wr  = wid >> 1, wc = wid & 1;
    const int mtile = blockIdx.x >> 6;      // 0..127
    const int ntile = blockIdx.x & 63;      // 0..63
    const int row0 = mtile * 128;
    const int col0 = ntile * 128;

    const int lg = l >> 4;                  // lane group 0..3
    const int lc = l & 15;

    // staging: per gld, 16 rows x 64B; lane l -> row (l>>2), dest slot (l&3).
    // LDS[row][s] holds global k-slot s ^ ((row>>1)&3)  (r8-verified formulas).
    const int srowoff = l >> 2;
    const int sslot   = (l & 3) ^ ((l >> 3) & 3);   // pre-swizzled source slot

    // 4 global_load_lds per thread per STAGE (2 A + 2 B)
    auto STAGE = [&](int buf, int kc) {
        const int k0 = kc * BKB;
        #pragma unroll
        for (int i = 0; i < 2; ++i) {
            int rbase = i * 64 + wid * 16;
            int row = rbase + srowoff;
            const s8* ga = A8 + (size_t)(row0 + row) * DDIM + k0 + sslot * 16;
            __builtin_amdgcn_global_load_lds(
                (const __attribute__((address_space(1))) void*)ga,
                (__attribute__((address_space(3))) void*)&Asb[buf][rbase * BKB], 16, 0, 0);
            const s8* gb = B8 + (size_t)(col0 + row) * DDIM + k0 + sslot * 16;
            __builtin_amdgcn_global_load_lds(
                (const __attribute__((address_space(1))) void*)gb,
                (__attribute__((address_space(3))) void*)&Bsb[buf][rbase * BKB], 16, 0, 0);
        }
    };

    v4i acc[4][4];
    #pragma unroll
    for (int m = 0; m < 4; ++m)
        #pragma unroll
        for (int n = 0; n < 4; ++n) acc[m][n] = (v4i){0, 0, 0, 0};

    STAGE(0, 0);
    int cur = 0;
    const int slotbyte = (lg ^ ((lc >> 1) & 3)) * 16;   // read swizzle (r8-verified)
    for (int kc = 0; kc < KCH; ++kc) {
        // RACE DISCIPLINE (r8-proven): our ds_reads of buf[cur^1] must COMPLETE
        // before we release B1 (which authorizes overwriting that buffer).
        asm volatile("s_waitcnt lgkmcnt(0)" ::: "memory");
        __builtin_amdgcn_sched_barrier(0);
        asm volatile("s_barrier" ::: "memory");          // B1
        if (kc < KCH - 1) {
            STAGE(cur ^ 1, kc + 1);
            asm volatile("s_waitcnt vmcnt(4)" ::: "memory");  // prev stage only
        } else {
            asm volatile("s_waitcnt vmcnt(0)" ::: "memory");
        }
        asm volatile("s_barrier" ::: "memory");          // B2

        v4i af[4], bf[4];
        #pragma unroll
        for (int m = 0; m < 4; ++m) {
            int row = wr * 64 + m * 16 + lc;
            af[m] = *(const v4i*)((const char*)&Asb[cur][0] + row * BKB + slotbyte);
        }
        #pragma unroll
        for (int n = 0; n < 4; ++n) {
            int row = wc * 64 + n * 16 + lc;
            bf[n] = *(const v4i*)((const char*)&Bsb[cur][0] + row * BKB + slotbyte);
        }
        #pragma unroll
        for (int m = 0; m < 4; ++m)
            #pragma unroll
            for (int n = 0; n < 4; ++n)
                acc[m][n] = __builtin_amdgcn_mfma_i32_16x16x64_i8(af[m], bf[n], acc[m][n], 0, 0, 0);
        cur ^= 1;
    }

    // ---- epilogue: per-row min over this block's 128 columns, packed u64 ----
    // D layout: col = lc, row = lg*4 + j (dtype-independent; verified r3/4/6/8)
    float c2v[4];
    #pragma unroll
    for (int n = 0; n < 4; ++n) c2v[n] = c2[col0 + wc * 64 + n * 16 + lc];

    #pragma unroll
    for (int m = 0; m < 4; ++m) {
        #pragma unroll
        for (int j = 0; j < 4; ++j) {
            int rloc = wr * 64 + m * 16 + lg * 4 + j;
            u64 best = ~0ull;
            #pragma unroll
            for (int n = 0; n < 4; ++n) {
                float s = c2v[n] - 2.0f * (float)acc[m][n][j] * QINV;
                u32 b = __float_as_uint(s);
                b = (b & 0x80000000u) ? ~b : (b | 0x80000000u);   // monotone float->u32
                int col = col0 + wc * 64 + n * 16 + lc;
                u64 key = ((u64)b << 32) | (u32)col;              // low bits: index tie-break
                best = key < best ? key : best;
            }
            #pragma unroll
            for (int off = 1; off < 16; off <<= 1) {
                u64 o = __shfl_xor(best, off);
                best = o < best ? o : best;
            }
            if (lc == 0) mergebuf[rloc][wc] = best;
        }
    }
    __syncthreads();   // full drain before cross-wave merge read
    if (tid < 128) {
        u64 a = mergebuf[tid][0], b = mergebuf[tid][1];
        part[(size_t)(row0 + tid) * NTILE + ntile] = a < b ? a : b;
    }
}

// ---- merge 64 winners -> top-4, fp64 recheck, quantize + idx + loss ------
__global__ void reduce_quant_kernel(const u64* __restrict__ part,
                                    const float* __restrict__ x, const float* __restrict__ cb,
                                    float* __restrict__ out, float* __restrict__ acc) {
    __shared__ float red[4];
    int t = blockIdx.x * 4 + (threadIdx.x >> 6);
    int l = threadIdx.x & 63;
    u64 k = part[(size_t)t * NTILE + l];

    int cand[4];
    #pragma unroll
    for (int c = 0; c < 4; ++c) {
        u64 m = k;
        #pragma unroll
        for (int off = 1; off < 64; off <<= 1) {
            u64 o = __shfl_xor(m, off);
            m = o < m ? o : m;
        }
        cand[c] = (int)(u32)(m & 0xffffffffull);
        if (k == m) k = ~0ull;        // keys unique (distinct cols) -> removes one lane
    }

    const float* xp = x + (size_t)t * DDIM + l * 8;
    float xv[8];
    #pragma unroll
    for (int j = 0; j < 8; ++j) xv[j] = xp[j];

    float cp[4][8];
    double d[4];
    #pragma unroll
    for (int c = 0; c < 4; ++c) {
        const float* cpp = cb + (size_t)cand[c] * DDIM + l * 8;
        double s = 0.0;
        #pragma unroll
        for (int j = 0; j < 8; ++j) {
            cp[c][j] = cpp[j];
            double a = (double)cp[c][j] - (double)xv[j];
            s += a * a;
        }
        d[c] = s;
    }
    #pragma unroll
    for (int c = 0; c < 4; ++c) {
        #pragma unroll
        for (int off = 1; off < 64; off <<= 1) d[c] += __shfl_xor(d[c], off);
    }

    double bd = d[0]; int bi = cand[0]; int bc = 0;
    #pragma unroll
    for (int c = 1; c < 4; ++c)
        if (d[c] < bd || (d[c] == bd && cand[c] < bi)) { bd = d[c]; bi = cand[c]; bc = c; }

    // winning code row (compile-time-indexed select, rule #20)
    float cw[8];
    #pragma unroll
    for (int j = 0; j < 8; ++j) {
        float v = cp[0][j];
        #pragma unroll
        for (int c = 1; c < 4; ++c) v = (bc == c) ? cp[c][j] : v;
        cw[j] = v;
    }

    // quantized out = x + (codes - x); loss partial = sum diff^2
    float ls = 0.f;
    float4 o0, o1;
    float dj[8];
    #pragma unroll
    for (int j = 0; j < 8; ++j) { dj[j] = cw[j] - xv[j]; ls += dj[j] * dj[j]; }
    o0.x = xv[0] + dj[0]; o0.y = xv[1] + dj[1]; o0.z = xv[2] + dj[2]; o0.w = xv[3] + dj[3];
    o1.x = xv[4] + dj[4]; o1.y = xv[5] + dj[5]; o1.z = xv[6] + dj[6]; o1.w = xv[7] + dj[7];
    float* op = out + (size_t)t * DDIM + l * 8;
    *(float4*)op = o0;
    *(float4*)(op + 4) = o1;

    if (l == 0) out[(size_t)M_TOK * DDIM + t] = (float)bi;   // index as fp32

    #pragma unroll
    for (int off = 32; off; off >>= 1) ls += __shfl_down(ls, off);
    int wv = threadIdx.x >> 6;
    if (l == 0) red[wv] = ls;
    __syncthreads();
    if (threadIdx.x == 0) atomicAdd(acc, red[0] + red[1] + red[2] + red[3]);
}

__global__ void loss_final_kernel(const float* __restrict__ acc, float* __restrict__ out) {
    if (threadIdx.x == 0 && blockIdx.x == 0) {
        float mean = (*acc) / (float)((size_t)M_TOK * DDIM);
        out[(size_t)M_TOK * DDIM + M_TOK] = 2.0f * mean;
    }
}

extern "C" void kernel_launch(void* const* d_in, const int* in_sizes, int n_in,
                              void* d_out, int out_size, void* d_ws, size_t ws_size,
                              hipStream_t stream) {
    const float* x  = (const float*)d_in[0];
    const float* cb = (const float*)d_in[1];
    float* out = (float*)d_out;
    char* ws = (char*)d_ws;

    s8*    A8   = (s8*)(ws + OFF_A8);
    s8*    B8   = (s8*)(ws + OFF_B8);
    u64*   part = (u64*)(ws + OFF_PART);
    float* c2   = (float*)(ws + OFF_C2);
    float* acc  = (float*)(ws + OFF_ACC);

    zero_kernel<<<1, 64, 0, stream>>>(acc);
    quant_cb_c2_kernel<<<NCODES / 4, 256, 0, stream>>>(cb, B8, c2);
    quant_x_kernel<<<(M_TOK * DDIM / 16) / 256, 256, 0, stream>>>(x, A8, M_TOK * DDIM / 16);
    gemm_top1_kernel<<<(M_TOK / 128) * NTILE, 256, 0, stream>>>(A8, B8, c2, part);
    reduce_quant_kernel<<<M_TOK / 4, 256, 0, stream>>>(part, x, cb, out, acc);
    loss_final_kernel<<<1, 64, 0, stream>>>(acc, out);
}